// Round 7
// baseline (6770.464 us; speedup 1.0000x reference)
//
#include <hip/hip_runtime.h>
#include <math.h>

namespace {

constexpr int NB = 1024;     // per-direction batch
constexpr int ND = 512;      // XDIM
constexpr int NH = 1024;     // hidden
constexpr int NM = 2048;     // stacked batch (fwd rows 0..1023, bwd 1024..2047)
constexpr int KTOT = 1024;   // GEMM K for all layers

typedef __attribute__((ext_vector_type(8))) short short8;
typedef __attribute__((ext_vector_type(4))) float floatx4;

__device__ __forceinline__ unsigned short f2bf(float f) {
  unsigned int u = __float_as_uint(f);
  unsigned int r = (u + 0x7FFFu + ((u >> 16) & 1u)) >> 16;
  return (unsigned short)r;
}
__device__ __forceinline__ float bf2f(unsigned short h) {
  return __uint_as_float(((unsigned int)h) << 16);
}
__device__ __forceinline__ void split2(float f, unsigned short& h, unsigned short& l) {
  h = f2bf(f);
  l = f2bf(f - bf2f(h));
}

__device__ __forceinline__ float wrap_angle(float x) {
  const float PI_F = 3.14159265358979323846f;
  const float TWO_PI = 6.28318530717958647692f;
  const float INV_TWO_PI = 0.15915494309189533577f;
  float y = x + PI_F;
  float r = y - TWO_PI * floorf(y * INV_TWO_PI);
  return r - PI_F;
}

// ---------------------------------------------------------------------------
// Weight prep: split-transpose f32 [K][N] -> bf16 hi/lo [rowoff+n][K]
// ---------------------------------------------------------------------------
__global__ __launch_bounds__(256) void tcvt_k(
    const float* __restrict__ in, int N,
    unsigned short* __restrict__ out_hi, unsigned short* __restrict__ out_lo,
    int rowoff)
{
  __shared__ float t[32][33];
  int tx = threadIdx.x, ty = threadIdx.y;
  int k0 = blockIdx.y * 32, n0 = blockIdx.x * 32;
#pragma unroll
  for (int i = 0; i < 4; ++i)
    t[ty * 4 + i][tx] = in[(size_t)(k0 + ty * 4 + i) * N + n0 + tx];
  __syncthreads();
#pragma unroll
  for (int i = 0; i < 4; ++i) {
    float f = t[tx][ty * 4 + i];
    unsigned short h, l;
    split2(f, h, l);
    size_t idx = (size_t)(rowoff + n0 + ty * 4 + i) * KTOT + k0 + tx;
    out_hi[idx] = h;
    out_lo[idx] = l;
  }
}

// ---------------------------------------------------------------------------
// Split-bf16 MFMA GEMM (3-term: Ah*Bh + Ah*Bl + Al*Bh), pre-split operands,
// ZERO LDS / ZERO barriers: each lane loads its MFMA fragments directly from
// global (16B contiguous per lane; L1/L2 serve the reuse). Every wave runs
// its K-loop independently -> max TLP, compiler-pipelined reg loads.
// M=2048, block tile 64x64 (4 waves, wave 32x32 via 2x2 16x16x32 frags).
// A = concat(A0,A1) halves (512 K each), row stride sA. B = [col][1024].
// ACT 1: tanh all; ACT 2: tanh unless col in [512,1024) (STQ mode).
// OUTF32 1: f32 out; 0: split bf16 out (oh, ol).
// ---------------------------------------------------------------------------
template <int ACT, int OUTF32>
__global__ __launch_bounds__(256) void gemm_k(
    const unsigned short* __restrict__ A0h, const unsigned short* __restrict__ A0l,
    const unsigned short* __restrict__ A1h, const unsigned short* __restrict__ A1l,
    int sA,
    const unsigned short* __restrict__ Bh, const unsigned short* __restrict__ Bl,
    const float* __restrict__ bias,
    float* __restrict__ outf,
    unsigned short* __restrict__ oh, unsigned short* __restrict__ ol,
    int ldo)
{
  const int tid = threadIdx.x, lane = tid & 63, w = tid >> 6;
  const int row0 = blockIdx.y * 64, col0 = blockIdx.x * 64;
  const int wr = w >> 1, wc = w & 1;
  const int rsel = lane & 15, ksel = lane >> 4;

  int arow[2], brow[2];
#pragma unroll
  for (int i = 0; i < 2; ++i) {
    arow[i] = row0 + wr * 32 + i * 16 + rsel;
    brow[i] = col0 + wc * 32 + i * 16 + rsel;
  }

  floatx4 acc[2][2];
#pragma unroll
  for (int i = 0; i < 2; ++i)
#pragma unroll
    for (int j = 0; j < 2; ++j) acc[i][j] = (floatx4)0.f;

#pragma unroll 2
  for (int kt = 0; kt < 32; ++kt) {          // 32 panels of K=32
    const int kk = kt * 32;                  // panel base (compile-time per iter)
    const unsigned short* Ah = (kk >= 512) ? A1h : A0h;
    const unsigned short* Al = (kk >= 512) ? A1l : A0l;
    const int ka = (kk & 511) + ksel * 8;
    const int kb = kk + ksel * 8;
    short8 ah8[2], al8[2], bh8[2], bl8[2];
#pragma unroll
    for (int i = 0; i < 2; ++i) {
      size_t ao = (size_t)arow[i] * sA + ka;
      ah8[i] = *reinterpret_cast<const short8*>(Ah + ao);
      al8[i] = *reinterpret_cast<const short8*>(Al + ao);
      size_t bo = (size_t)brow[i] * KTOT + kb;
      bh8[i] = *reinterpret_cast<const short8*>(Bh + bo);
      bl8[i] = *reinterpret_cast<const short8*>(Bl + bo);
    }
#pragma unroll
    for (int i = 0; i < 2; ++i)
#pragma unroll
      for (int j = 0; j < 2; ++j) {
        acc[i][j] = __builtin_amdgcn_mfma_f32_16x16x32_bf16(
            ah8[i], bh8[j], acc[i][j], 0, 0, 0);
        acc[i][j] = __builtin_amdgcn_mfma_f32_16x16x32_bf16(
            ah8[i], bl8[j], acc[i][j], 0, 0, 0);
        acc[i][j] = __builtin_amdgcn_mfma_f32_16x16x32_bf16(
            al8[i], bh8[j], acc[i][j], 0, 0, 0);
      }
  }

  // ---- epilogue ----
#pragma unroll
  for (int i = 0; i < 2; ++i)
#pragma unroll
    for (int j = 0; j < 2; ++j) {
      int gr = row0 + wr * 32 + i * 16 + ksel * 4;
      int gc = col0 + wc * 32 + j * 16 + rsel;
      float bb = bias[gc];
      bool dt = (ACT == 1) || (ACT == 2 && !(gc >= 512 && gc < 1024));
#pragma unroll
      for (int rg = 0; rg < 4; ++rg) {
        float v = acc[i][j][rg] + bb;
        if (dt) v = tanhf(v);
        if constexpr (OUTF32) {
          outf[(size_t)(gr + rg) * ldo + gc] = v;
        } else {
          unsigned short h, l;
          split2(v, h, l);
          oh[(size_t)(gr + rg) * ldo + gc] = h;
          ol[(size_t)(gr + rg) * ldo + gc] = l;
        }
      }
    }
}

// ---------------------------------------------------------------------------
// grad of action (+ split mirrors), 128 threads per row
// ---------------------------------------------------------------------------
__device__ __forceinline__ void grad_from_lds(
    const float* xsh, float* sp, float beta, int row,
    float* __restrict__ g, unsigned short* __restrict__ gh,
    unsigned short* __restrict__ gl)
{
  int s0 = threadIdx.x * 2;
#pragma unroll
  for (int u = 0; u < 2; ++u) {
    int s = s0 + u, tt = s >> 4, l = s & 15;
    float p = xsh[s * 2] - xsh[s * 2 + 1]
            - xsh[(tt * 16 + ((l + 1) & 15)) * 2]
            + xsh[(((tt + 1) & 15) * 16 + l) * 2 + 1];
    sp[s] = sinf(p);
  }
  __syncthreads();
  float* gr = g + (size_t)row * ND;
  unsigned short* ghr = gh + (size_t)row * ND;
  unsigned short* glr = gl + (size_t)row * ND;
#pragma unroll
  for (int u = 0; u < 2; ++u) {
    int s = s0 + u, tt = s >> 4, l = s & 15;
    float g0 = beta * (sp[s] - sp[tt * 16 + ((l - 1) & 15)]);
    float g1 = beta * (sp[((tt - 1) & 15) * 16 + l] - sp[s]);
    gr[s * 2] = g0;
    gr[s * 2 + 1] = g1;
    unsigned short h0, l0, h1v, l1v;
    split2(g0, h0, l0);
    split2(g1, h1v, l1v);
    ghr[s * 2] = h0; glr[s * 2] = l0;
    ghr[s * 2 + 1] = h1v; glr[s * 2 + 1] = l1v;
  }
}

__global__ __launch_bounds__(128) void grad_k(
    const float* __restrict__ xs, const float* __restrict__ betap,
    float* __restrict__ g, unsigned short* __restrict__ gh,
    unsigned short* __restrict__ gl)
{
  __shared__ float xsh[512];
  __shared__ float sp[256];
  int row = blockIdx.x, c = threadIdx.x << 2;
  float4 x4 = *reinterpret_cast<const float4*>(xs + (size_t)row * ND + c);
  xsh[c] = x4.x; xsh[c + 1] = x4.y; xsh[c + 2] = x4.z; xsh[c + 3] = x4.w;
  __syncthreads();
  grad_from_lds(xsh, sp, betap[0], row, g, gh, gl);
}

// ---------------------------------------------------------------------------
// init: copy states, split mirrors, pre-masked x for the first xnet
// ---------------------------------------------------------------------------
__global__ __launch_bounds__(128) void init_k(
    const float* __restrict__ x_in, const float* __restrict__ v_in,
    const float* __restrict__ m0F, const float* __restrict__ m0B,
    float* __restrict__ xs, float* __restrict__ vs,
    unsigned short* __restrict__ xh, unsigned short* __restrict__ xl,
    unsigned short* __restrict__ xmh, unsigned short* __restrict__ xml,
    unsigned short* __restrict__ vh, unsigned short* __restrict__ vl,
    float* __restrict__ ld)
{
  int row = blockIdx.x;
  bool fwd = row < NB;
  int c = threadIdx.x << 2;
  size_t off = (size_t)row * ND + c;
  const float* xr = x_in + (size_t)(fwd ? row : row - NB) * ND + c;
  const float* vr = v_in + off;
  const float* mk = (fwd ? m0F : m0B) + c;
  float4 x4 = *reinterpret_cast<const float4*>(xr);
  float4 v4 = *reinterpret_cast<const float4*>(vr);
  float4 m4 = *reinterpret_cast<const float4*>(mk);
  float xx[4] = {x4.x, x4.y, x4.z, x4.w};
  float vv[4] = {v4.x, v4.y, v4.z, v4.w};
  float mm[4] = {m4.x, m4.y, m4.z, m4.w};
  ushort4 xhv, xlv, xmhv, xmlv, vhv, vlv;
  unsigned short* ph = (unsigned short*)&xhv;
  unsigned short* pl = (unsigned short*)&xlv;
  unsigned short* pmh = (unsigned short*)&xmhv;
  unsigned short* pml = (unsigned short*)&xmlv;
  unsigned short* pvh = (unsigned short*)&vhv;
  unsigned short* pvl = (unsigned short*)&vlv;
#pragma unroll
  for (int j = 0; j < 4; ++j) {
    float m = fwd ? mm[j] : 1.f - mm[j];   // bwd first mask inverted
    split2(xx[j], ph[j], pl[j]);
    split2(m * xx[j], pmh[j], pml[j]);
    split2(vv[j], pvh[j], pvl[j]);
  }
  *reinterpret_cast<float4*>(xs + off) = make_float4(xx[0], xx[1], xx[2], xx[3]);
  *reinterpret_cast<float4*>(vs + off) = make_float4(vv[0], vv[1], vv[2], vv[3]);
  *reinterpret_cast<ushort4*>(xh + off) = xhv;
  *reinterpret_cast<ushort4*>(xl + off) = xlv;
  *reinterpret_cast<ushort4*>(xmh + off) = xmhv;
  *reinterpret_cast<ushort4*>(xml + off) = xmlv;
  *reinterpret_cast<ushort4*>(vh + off) = vhv;
  *reinterpret_cast<ushort4*>(vl + off) = vlv;
  if (threadIdx.x == 0) ld[row] = 0.f;
}

// ---------------------------------------------------------------------------
// v update (optionally applied twice: trailing half-step of step s + leading
// half-step of step s+1 use identical S,T,Q,g); split mirrors.
// ---------------------------------------------------------------------------
__global__ __launch_bounds__(128) void upd_v_k(
    float* __restrict__ vs, const float* __restrict__ g,
    const float* __restrict__ STQ,
    const float* __restrict__ epsp, float* __restrict__ ld,
    unsigned short* __restrict__ vh, unsigned short* __restrict__ vl,
    int twice)
{
  int row = blockIdx.x;
  bool fwd = row < NB;
  int c = threadIdx.x << 2;
  float eps = epsp[0];
  size_t off = (size_t)row * ND + c;
  const float* sr = STQ + (size_t)row * 1536;
  float4 v4 = *reinterpret_cast<float4*>(vs + off);
  float4 g4 = *reinterpret_cast<const float4*>(g + off);
  float4 S4 = *reinterpret_cast<const float4*>(sr + c);
  float4 T4 = *reinterpret_cast<const float4*>(sr + 512 + c);
  float4 Q4 = *reinterpret_cast<const float4*>(sr + 1024 + c);
  float vv[4] = {v4.x, v4.y, v4.z, v4.w};
  float gg[4] = {g4.x, g4.y, g4.z, g4.w};
  float ss[4] = {S4.x, S4.y, S4.z, S4.w};
  float tt[4] = {T4.x, T4.y, T4.z, T4.w};
  float qq[4] = {Q4.x, Q4.y, Q4.z, Q4.w};
  float scsum = 0.f;
  ushort4 hv, lv;
  unsigned short* ph = (unsigned short*)&hv;
  unsigned short* pl = (unsigned short*)&lv;
#pragma unroll
  for (int j = 0; j < 4; ++j) {
    float sc = (fwd ? 0.5f : -0.5f) * eps * ss[j];
    float F = gg[j] * expf(eps * qq[j]) + tt[j];
    vv[j] = fwd ? vv[j] * expf(sc) - 0.5f * eps * F
                : expf(sc) * (vv[j] + 0.5f * eps * F);
    scsum += sc;
    if (twice) {
      vv[j] = fwd ? vv[j] * expf(sc) - 0.5f * eps * F
                  : expf(sc) * (vv[j] + 0.5f * eps * F);
      scsum += sc;
    }
    split2(vv[j], ph[j], pl[j]);
  }
  *reinterpret_cast<float4*>(vs + off) = make_float4(vv[0], vv[1], vv[2], vv[3]);
  *reinterpret_cast<ushort4*>(vh + off) = hv;
  *reinterpret_cast<ushort4*>(vl + off) = lv;
  for (int o = 32; o > 0; o >>= 1) scsum += __shfl_down(scsum, o);
  __shared__ float part[2];
  if ((threadIdx.x & 63) == 0) part[threadIdx.x >> 6] = scsum;
  __syncthreads();
  if (threadIdx.x == 0) ld[row] += part[0] + part[1];
}

// ---------------------------------------------------------------------------
// x update + fused grad recompute + split mirrors (x, masked-x-for-next, g)
// ---------------------------------------------------------------------------
__global__ __launch_bounds__(128) void upd_x_k(
    float* __restrict__ xs, const float* __restrict__ vs,
    const float* __restrict__ STQ,
    const float* __restrict__ maskF, int invF,
    const float* __restrict__ maskB, int invB,
    const float* __restrict__ nmF, int niF,
    const float* __restrict__ nmB, int niB,
    const float* __restrict__ epsp, const float* __restrict__ betap,
    float* __restrict__ g, float* __restrict__ ld,
    unsigned short* __restrict__ xh, unsigned short* __restrict__ xl,
    unsigned short* __restrict__ xmh, unsigned short* __restrict__ xml,
    unsigned short* __restrict__ gh, unsigned short* __restrict__ gl)
{
  __shared__ float xsh[512];
  __shared__ float sp[256];
  int row = blockIdx.x;
  bool fwd = row < NB;
  const float* mk = fwd ? maskF : maskB;
  const float* nmk = fwd ? nmF : nmB;
  int inv = fwd ? invF : invB;
  int ninv = fwd ? niF : niB;
  int c = threadIdx.x << 2;
  float eps = epsp[0];
  size_t off = (size_t)row * ND + c;
  const float* sr = STQ + (size_t)row * 1536;
  float4 x4 = *reinterpret_cast<float4*>(xs + off);
  float4 v4 = *reinterpret_cast<const float4*>(vs + off);
  float4 m4 = *reinterpret_cast<const float4*>(mk + c);
  float4 n4 = *reinterpret_cast<const float4*>(nmk + c);
  float4 S4 = *reinterpret_cast<const float4*>(sr + c);
  float4 T4 = *reinterpret_cast<const float4*>(sr + 512 + c);
  float4 Q4 = *reinterpret_cast<const float4*>(sr + 1024 + c);
  float xx[4] = {x4.x, x4.y, x4.z, x4.w};
  float vv[4] = {v4.x, v4.y, v4.z, v4.w};
  float mm[4] = {m4.x, m4.y, m4.z, m4.w};
  float nn[4] = {n4.x, n4.y, n4.z, n4.w};
  float ss[4] = {S4.x, S4.y, S4.z, S4.w};
  float tt[4] = {T4.x, T4.y, T4.z, T4.w};
  float qq[4] = {Q4.x, Q4.y, Q4.z, Q4.w};
  float scsum = 0.f;
  float xn[4];
  ushort4 hv, lv, mhv, mlv;
  unsigned short* ph = (unsigned short*)&hv;
  unsigned short* pl = (unsigned short*)&lv;
  unsigned short* pmh = (unsigned short*)&mhv;
  unsigned short* pml = (unsigned short*)&mlv;
#pragma unroll
  for (int j = 0; j < 4; ++j) {
    float m = inv ? 1.f - mm[j] : mm[j];
    float mb = 1.f - m;
    float es = eps * ss[j];
    float F = vv[j] * expf(eps * qq[j]) + tt[j];
    float t;
    if (fwd) {
      t = m * xx[j] + mb * (xx[j] * expf(es) + eps * F);
      scsum += mb * es;
    } else {
      t = m * xx[j] + mb * (expf(-es) * (xx[j] - eps * F));
      scsum -= mb * es;
    }
    xn[j] = wrap_angle(t);
    xsh[c + j] = xn[j];
    float nm = ninv ? 1.f - nn[j] : nn[j];
    split2(xn[j], ph[j], pl[j]);
    split2(nm * xn[j], pmh[j], pml[j]);
  }
  *reinterpret_cast<float4*>(xs + off) = make_float4(xn[0], xn[1], xn[2], xn[3]);
  *reinterpret_cast<ushort4*>(xh + off) = hv;
  *reinterpret_cast<ushort4*>(xl + off) = lv;
  *reinterpret_cast<ushort4*>(xmh + off) = mhv;
  *reinterpret_cast<ushort4*>(xml + off) = mlv;
  __syncthreads();
  grad_from_lds(xsh, sp, betap[0], row, g, gh, gl);
  for (int o = 32; o > 0; o >>= 1) scsum += __shfl_down(scsum, o);
  __shared__ float part[2];
  if ((threadIdx.x & 63) == 0) part[threadIdx.x >> 6] = scsum;
  __syncthreads();
  if (threadIdx.x == 0) ld[row] += part[0] + part[1];
}

// ---------------------------------------------------------------------------
// finalize (stacked state)
// ---------------------------------------------------------------------------
__global__ __launch_bounds__(256) void finalize_k(
    const float* __restrict__ x_in, const float* __restrict__ v_in,
    const float* __restrict__ xs, const float* __restrict__ vs,
    const float* __restrict__ ld,
    const float* __restrict__ rdir, const float* __restrict__ racc,
    const float* __restrict__ betap,
    float* __restrict__ out_x, float* __restrict__ out_px,
    float* __restrict__ out_sld)
{
  int b = blockIdx.x, t = threadIdx.x;
  bool fwd = rdir[b] < 0.5f;
  int prow = fwd ? b : NB + b;
  const float* xp = xs + (size_t)prow * ND;
  const float* vp = vs + (size_t)prow * ND;
  const float* vi = v_in + (size_t)(fwd ? 0 : NB) * ND + (size_t)b * ND;
  float sld = ld[prow];
  __shared__ float xs0[512], xs1[512];
  const float* xr = x_in + (size_t)b * ND;
  xs0[t] = xr[t]; xs0[t + 256] = xr[t + 256];
  xs1[t] = xp[t]; xs1[t + 256] = xp[t + 256];
  __syncthreads();
  int tt = t >> 4, l = t & 15;
  int i00 = t * 2, i01 = t * 2 + 1;
  int i10 = (tt * 16 + ((l + 1) & 15)) * 2;
  int i11 = (((tt + 1) & 15) * 16 + l) * 2 + 1;
  float p0 = xs0[i00] - xs0[i01] - xs0[i10] + xs0[i11];
  float p1 = xs1[i00] - xs1[i01] - xs1[i10] + xs1[i11];
  float r0 = 1.f - cosf(p0);
  float r1 = 1.f - cosf(p1);
  float a0v = vi[t], a1v = vi[t + 256];
  float b0v = vp[t], b1v = vp[t + 256];
  float svi = a0v * a0v + a1v * a1v;
  float svp = b0v * b0v + b1v * b1v;
  for (int o = 32; o > 0; o >>= 1) {
    r0  += __shfl_down(r0, o);
    r1  += __shfl_down(r1, o);
    svi += __shfl_down(svi, o);
    svp += __shfl_down(svp, o);
  }
  __shared__ float red[4][4];
  if ((t & 63) == 0) {
    int w = t >> 6;
    red[w][0] = r0; red[w][1] = r1; red[w][2] = svi; red[w][3] = svp;
  }
  __syncthreads();
  __shared__ float px_s;
  if (t == 0) {
    float R0 = 0, R1 = 0, SI = 0, SP = 0;
    for (int w = 0; w < 4; ++w) {
      R0 += red[w][0]; R1 += red[w][1]; SI += red[w][2]; SP += red[w][3];
    }
    float beta = betap[0];
    float h_init = beta * R0 + 0.5f * SI;
    float h_prop = beta * R1 + 0.5f * SP;
    px_s = expf(fminf(h_init - h_prop + sld, 0.f));
  }
  __syncthreads();
  float px = px_s;
  bool ma = racc[b] < px;
  float* ox = out_x + (size_t)b * ND;
  ox[t]       = wrap_angle(ma ? xs1[t]       : xs0[t]);
  ox[t + 256] = wrap_angle(ma ? xs1[t + 256] : xs0[t + 256]);
  if (t == 0) {
    out_px[b] = px;
    out_sld[b] = ma ? sld : 0.f;
  }
}

}  // namespace

extern "C" void kernel_launch(void* const* d_in, const int* in_sizes, int n_in,
                              void* d_out, int out_size, void* d_ws, size_t ws_size,
                              hipStream_t stream)
{
  const float* x_in = (const float*)d_in[0];
  const float* v_in = (const float*)d_in[1];
  const float* epsp = (const float*)d_in[2];
  const float* betap = (const float*)d_in[3];
  const float* rdir = (const float*)d_in[4];
  const float* racc = (const float*)d_in[5];
  const float* masks = (const float*)d_in[6];
  const float* xW1 = (const float*)d_in[7];
  const float* xb1 = (const float*)d_in[8];
  const float* xW2 = (const float*)d_in[9];
  const float* xb2 = (const float*)d_in[10];
  const float* xWs = (const float*)d_in[11];
  const float* xbs = (const float*)d_in[12];
  const float* xWt = (const float*)d_in[13];
  const float* xbt = (const float*)d_in[14];
  const float* xWq = (const float*)d_in[15];
  const float* xbq = (const float*)d_in[16];
  const float* vW1 = (const float*)d_in[17];
  const float* vb1 = (const float*)d_in[18];
  const float* vW2 = (const float*)d_in[19];
  const float* vb2 = (const float*)d_in[20];
  const float* vWs = (const float*)d_in[21];
  const float* vbs = (const float*)d_in[22];
  const float* vWt = (const float*)d_in[23];
  const float* vbt = (const float*)d_in[24];
  const float* vWq = (const float*)d_in[25];
  const float* vbq = (const float*)d_in[26];

  char* base = (char*)d_ws;
  auto alloc = [&](size_t bytes) {
    char* r = base;
    base += (bytes + 255) & ~(size_t)255;
    return r;
  };
  float* xs = (float*)alloc((size_t)NM * ND * 4);
  float* vs = (float*)alloc((size_t)NM * ND * 4);
  float* g  = (float*)alloc((size_t)NM * ND * 4);
  float* ld = (float*)alloc((size_t)NM * 4);
  unsigned short* xh  = (unsigned short*)alloc((size_t)NM * ND * 2);
  unsigned short* xl  = (unsigned short*)alloc((size_t)NM * ND * 2);
  unsigned short* xmh = (unsigned short*)alloc((size_t)NM * ND * 2);
  unsigned short* xml = (unsigned short*)alloc((size_t)NM * ND * 2);
  unsigned short* vh  = (unsigned short*)alloc((size_t)NM * ND * 2);
  unsigned short* vl  = (unsigned short*)alloc((size_t)NM * ND * 2);
  unsigned short* gh  = (unsigned short*)alloc((size_t)NM * ND * 2);
  unsigned short* gl  = (unsigned short*)alloc((size_t)NM * ND * 2);
  unsigned short* h1h = (unsigned short*)alloc((size_t)NM * NH * 2);
  unsigned short* h1l = (unsigned short*)alloc((size_t)NM * NH * 2);
  unsigned short* h2h = (unsigned short*)alloc((size_t)NM * NH * 2);
  unsigned short* h2l = (unsigned short*)alloc((size_t)NM * NH * 2);
  float* STQ = (float*)alloc((size_t)NM * 1536 * 4);
  unsigned short* xW1h = (unsigned short*)alloc((size_t)NH * KTOT * 2);
  unsigned short* xW1l = (unsigned short*)alloc((size_t)NH * KTOT * 2);
  unsigned short* xW2h = (unsigned short*)alloc((size_t)NH * KTOT * 2);
  unsigned short* xW2l = (unsigned short*)alloc((size_t)NH * KTOT * 2);
  unsigned short* xWsh = (unsigned short*)alloc((size_t)1536 * KTOT * 2);
  unsigned short* xWsl = (unsigned short*)alloc((size_t)1536 * KTOT * 2);
  unsigned short* vW1h = (unsigned short*)alloc((size_t)NH * KTOT * 2);
  unsigned short* vW1l = (unsigned short*)alloc((size_t)NH * KTOT * 2);
  unsigned short* vW2h = (unsigned short*)alloc((size_t)NH * KTOT * 2);
  unsigned short* vW2l = (unsigned short*)alloc((size_t)NH * KTOT * 2);
  unsigned short* vWsh = (unsigned short*)alloc((size_t)1536 * KTOT * 2);
  unsigned short* vWsl = (unsigned short*)alloc((size_t)1536 * KTOT * 2);
  float* bstq_x = (float*)alloc(1536 * 4);
  float* bstq_v = (float*)alloc(1536 * 4);

  // ---- weight prep ----
  dim3 tb(32, 8);
  tcvt_k<<<dim3(32, 32), tb, 0, stream>>>(xW1, 1024, xW1h, xW1l, 0);
  tcvt_k<<<dim3(32, 32), tb, 0, stream>>>(xW2, 1024, xW2h, xW2l, 0);
  tcvt_k<<<dim3(16, 32), tb, 0, stream>>>(xWs, 512, xWsh, xWsl, 0);
  tcvt_k<<<dim3(16, 32), tb, 0, stream>>>(xWt, 512, xWsh, xWsl, 512);
  tcvt_k<<<dim3(16, 32), tb, 0, stream>>>(xWq, 512, xWsh, xWsl, 1024);
  tcvt_k<<<dim3(32, 32), tb, 0, stream>>>(vW1, 1024, vW1h, vW1l, 0);
  tcvt_k<<<dim3(32, 32), tb, 0, stream>>>(vW2, 1024, vW2h, vW2l, 0);
  tcvt_k<<<dim3(16, 32), tb, 0, stream>>>(vWs, 512, vWsh, vWsl, 0);
  tcvt_k<<<dim3(16, 32), tb, 0, stream>>>(vWt, 512, vWsh, vWsl, 512);
  tcvt_k<<<dim3(16, 32), tb, 0, stream>>>(vWq, 512, vWsh, vWsl, 1024);
  hipMemcpyAsync(bstq_x,        xbs, 512 * 4, hipMemcpyDeviceToDevice, stream);
  hipMemcpyAsync(bstq_x + 512,  xbt, 512 * 4, hipMemcpyDeviceToDevice, stream);
  hipMemcpyAsync(bstq_x + 1024, xbq, 512 * 4, hipMemcpyDeviceToDevice, stream);
  hipMemcpyAsync(bstq_v,        vbs, 512 * 4, hipMemcpyDeviceToDevice, stream);
  hipMemcpyAsync(bstq_v + 512,  vbt, 512 * 4, hipMemcpyDeviceToDevice, stream);
  hipMemcpyAsync(bstq_v + 1024, vbq, 512 * 4, hipMemcpyDeviceToDevice, stream);

  // ---- state init (rows 0..1023 fwd, 1024..2047 bwd) ----
  init_k<<<NM, 128, 0, stream>>>(x_in, v_in, masks, masks + 9 * ND,
                                 xs, vs, xh, xl, xmh, xml, vh, vl, ld);
  grad_k<<<NM, 128, 0, stream>>>(xs, betap, g, gh, gl);

  auto vnet = [&]() {
    gemm_k<1, 0><<<dim3(16, 32), 256, 0, stream>>>(
        xh, xl, gh, gl, 512, vW1h, vW1l, vb1, nullptr, h1h, h1l, NH);
    gemm_k<1, 0><<<dim3(16, 32), 256, 0, stream>>>(
        h1h, h1l, h1h + 512, h1l + 512, 1024, vW2h, vW2l, vb2,
        nullptr, h2h, h2l, NH);
    gemm_k<2, 1><<<dim3(24, 32), 256, 0, stream>>>(
        h2h, h2l, h2h + 512, h2l + 512, 1024, vWsh, vWsl, bstq_v,
        STQ, nullptr, nullptr, 1536);
  };
  auto xnet = [&]() {
    gemm_k<1, 0><<<dim3(16, 32), 256, 0, stream>>>(
        vh, vl, xmh, xml, 512, xW1h, xW1l, xb1, nullptr, h1h, h1l, NH);
    gemm_k<1, 0><<<dim3(16, 32), 256, 0, stream>>>(
        h1h, h1l, h1h + 512, h1l + 512, 1024, xW2h, xW2l, xb2,
        nullptr, h2h, h2l, NH);
    gemm_k<2, 1><<<dim3(24, 32), 256, 0, stream>>>(
        h2h, h2l, h2h + 512, h2l + 512, 1024, xWsh, xWsl, bstq_x,
        STQ, nullptr, nullptr, 1536);
  };

  // STQ_v for x_0, then step 0's leading v half-step (single)
  vnet();
  upd_v_k<<<NM, 128, 0, stream>>>(vs, g, STQ, epsp, ld, vh, vl, 0);
  for (int s = 0; s < 10; ++s) {
    const float* mF = masks + (size_t)s * ND;
    const float* mB = masks + (size_t)(9 - s) * ND;
    const float* mFn = masks + (size_t)((s + 1 < 10) ? s + 1 : 0) * ND;
    const float* mBn = masks + (size_t)((s + 1 < 10) ? 8 - s : 0) * ND;
    // x sub-step 1: fwd m, bwd 1-m; next consumer mask: fwd 1-m, bwd m
    xnet();
    upd_x_k<<<NM, 128, 0, stream>>>(xs, vs, STQ, mF, 0, mB, 1, mF, 1, mB, 0,
                                    epsp, betap, g, ld,
                                    xh, xl, xmh, xml, gh, gl);
    // x sub-step 2: fwd 1-m, bwd m; next: step s+1 sub1 (fwd m', bwd 1-m')
    xnet();
    upd_x_k<<<NM, 128, 0, stream>>>(xs, vs, STQ, mF, 1, mB, 0, mFn, 0, mBn, 1,
                                    epsp, betap, g, ld,
                                    xh, xl, xmh, xml, gh, gl);
    // vnet on NEW x serves trailing half-step of s AND leading of s+1
    vnet();
    upd_v_k<<<NM, 128, 0, stream>>>(vs, g, STQ, epsp, ld, vh, vl,
                                    (s < 9) ? 1 : 0);
  }

  float* out_x = (float*)d_out;
  float* out_px = out_x + (size_t)NB * ND;
  float* out_sld = out_px + NB;
  finalize_k<<<NB, 256, 0, stream>>>(x_in, v_in, xs, vs, ld, rdir, racc, betap,
                                     out_x, out_px, out_sld);
}

// Round 8
// 2491.472 us; speedup vs baseline: 2.7175x; 2.7175x over previous
//
#include <hip/hip_runtime.h>
#include <math.h>

namespace {

constexpr int NB = 1024;     // per-direction batch
constexpr int ND = 512;      // XDIM
constexpr int NH = 1024;     // hidden
constexpr int NM = 2048;     // stacked batch (fwd rows 0..1023, bwd 1024..2047)
constexpr int KTOT = 1024;   // GEMM K for all layers

typedef __attribute__((ext_vector_type(8))) short short8;
typedef __attribute__((ext_vector_type(4))) float floatx4;

__device__ __forceinline__ unsigned short f2bf(float f) {
  unsigned int u = __float_as_uint(f);
  unsigned int r = (u + 0x7FFFu + ((u >> 16) & 1u)) >> 16;
  return (unsigned short)r;
}
__device__ __forceinline__ float bf2f(unsigned short h) {
  return __uint_as_float(((unsigned int)h) << 16);
}
__device__ __forceinline__ void split2(float f, unsigned short& h, unsigned short& l) {
  h = f2bf(f);
  l = f2bf(f - bf2f(h));
}

__device__ __forceinline__ float wrap_angle(float x) {
  const float PI_F = 3.14159265358979323846f;
  const float TWO_PI = 6.28318530717958647692f;
  const float INV_TWO_PI = 0.15915494309189533577f;
  float y = x + PI_F;
  float r = y - TWO_PI * floorf(y * INV_TWO_PI);
  return r - PI_F;
}

// ---------------------------------------------------------------------------
// Weight prep: split-transpose f32 [K][N] -> bf16 hi/lo [rowoff+n][K]
// ---------------------------------------------------------------------------
__global__ __launch_bounds__(256) void tcvt_k(
    const float* __restrict__ in, int N,
    unsigned short* __restrict__ out_hi, unsigned short* __restrict__ out_lo,
    int rowoff)
{
  __shared__ float t[32][33];
  int tx = threadIdx.x, ty = threadIdx.y;
  int k0 = blockIdx.y * 32, n0 = blockIdx.x * 32;
#pragma unroll
  for (int i = 0; i < 4; ++i)
    t[ty * 4 + i][tx] = in[(size_t)(k0 + ty * 4 + i) * N + n0 + tx];
  __syncthreads();
#pragma unroll
  for (int i = 0; i < 4; ++i) {
    float f = t[tx][ty * 4 + i];
    unsigned short h, l;
    split2(f, h, l);
    size_t idx = (size_t)(rowoff + n0 + ty * 4 + i) * KTOT + k0 + tx;
    out_hi[idx] = h;
    out_lo[idx] = l;
  }
}

// ---------------------------------------------------------------------------
// Split-bf16 MFMA GEMM (3-term: Ah*Bh + Ah*Bl + Al*Bh), pre-split operands.
// r3-proven schedule: reg-staged global->LDS (loads for kt+1 issued BEFORE the
// MFMA cluster; vmcnt waits land at the ds_write after the barrier), single
// 32 KiB LDS buffer, BK=64, 2 barriers/kt. kg^(row&7) swizzle (0 conflicts).
// M=2048, tile 64x64, 4 waves, wave 32x32 via 2x2 16x16x32 frags.
// A = concat(A0,A1) halves (512 K each), row stride sA; BK tiles never
// straddle the 512 boundary. B = [col][1024].
// ACT 1: tanh all; ACT 2: tanh unless col in [512,1024) (STQ mode).
// OUTF32 1: f32 out; 0: split bf16 out (oh, ol).
// ---------------------------------------------------------------------------
template <int ACT, int OUTF32>
__global__ __launch_bounds__(256) void gemm_k(
    const unsigned short* __restrict__ A0h, const unsigned short* __restrict__ A0l,
    const unsigned short* __restrict__ A1h, const unsigned short* __restrict__ A1l,
    int sA,
    const unsigned short* __restrict__ Bh, const unsigned short* __restrict__ Bl,
    const float* __restrict__ bias,
    float* __restrict__ outf,
    unsigned short* __restrict__ oh, unsigned short* __restrict__ ol,
    int ldo)
{
  __shared__ __align__(16) unsigned short As_h[64 * 64];
  __shared__ __align__(16) unsigned short As_l[64 * 64];
  __shared__ __align__(16) unsigned short Bs_h[64 * 64];
  __shared__ __align__(16) unsigned short Bs_l[64 * 64];

  const int tid = threadIdx.x, lane = tid & 63, w = tid >> 6;
  const int row0 = blockIdx.y * 64, col0 = blockIdx.x * 64;

  // staging geometry: thread t -> local row t>>2 (A-row / B-col), slots
  // s2, s2+1 (each slot = 8 k = 16B); 256 thr cover 64 rows x 64 k.
  const int arl = tid >> 2;
  const int s2 = (tid & 3) * 2;
  const int wofs0 = arl * 64 + ((s2 ^ (arl & 7)) * 8);
  const int wofs1 = arl * 64 + (((s2 + 1) ^ (arl & 7)) * 8);

  short8 rah0, rah1, ral0, ral1, rbh0, rbh1, rbl0, rbl1;

  auto load_regs = [&](int kt) {
    // A: BK tile lies entirely in one 512-half (kbase+56 < 512 for kt&7)
    const unsigned short* Ah = (kt >= 8) ? A1h : A0h;
    const unsigned short* Al = (kt >= 8) ? A1l : A0l;
    const int ka = (kt & 7) * 64 + s2 * 8;
    size_t ao = (size_t)(row0 + arl) * sA + ka;
    rah0 = *reinterpret_cast<const short8*>(Ah + ao);
    rah1 = *reinterpret_cast<const short8*>(Ah + ao + 8);
    ral0 = *reinterpret_cast<const short8*>(Al + ao);
    ral1 = *reinterpret_cast<const short8*>(Al + ao + 8);
    const int kb = kt * 64 + s2 * 8;
    size_t bo = (size_t)(col0 + arl) * KTOT + kb;
    rbh0 = *reinterpret_cast<const short8*>(Bh + bo);
    rbh1 = *reinterpret_cast<const short8*>(Bh + bo + 8);
    rbl0 = *reinterpret_cast<const short8*>(Bl + bo);
    rbl1 = *reinterpret_cast<const short8*>(Bl + bo + 8);
  };

  // fragment read offsets (swizzled): kgr in 0..7 (64 k / 8)
  const int wr = w >> 1, wc = w & 1;
  const int rsel = lane & 15, ksel = lane >> 4;
  int arow[2], brow[2];
#pragma unroll
  for (int i = 0; i < 2; ++i) {
    arow[i] = wr * 32 + i * 16 + rsel;
    brow[i] = wc * 32 + i * 16 + rsel;
  }

  floatx4 acc[2][2];
#pragma unroll
  for (int i = 0; i < 2; ++i)
#pragma unroll
    for (int j = 0; j < 2; ++j) acc[i][j] = (floatx4)0.f;

  load_regs(0);

  for (int kt = 0; kt < 16; ++kt) {
    __syncthreads();   // prior iteration's frag reads done before overwrite
    *reinterpret_cast<short8*>(As_h + wofs0) = rah0;
    *reinterpret_cast<short8*>(As_h + wofs1) = rah1;
    *reinterpret_cast<short8*>(As_l + wofs0) = ral0;
    *reinterpret_cast<short8*>(As_l + wofs1) = ral1;
    *reinterpret_cast<short8*>(Bs_h + wofs0) = rbh0;
    *reinterpret_cast<short8*>(Bs_h + wofs1) = rbh1;
    *reinterpret_cast<short8*>(Bs_l + wofs0) = rbl0;
    *reinterpret_cast<short8*>(Bs_l + wofs1) = rbl1;
    __syncthreads();
    if (kt < 15) load_regs(kt + 1);   // issue early; latency hides under MFMA
#pragma unroll
    for (int ks = 0; ks < 2; ++ks) {
      const int kgr = ks * 4 + ksel;
      short8 ah8[2], al8[2], bh8[2], bl8[2];
#pragma unroll
      for (int i = 0; i < 2; ++i) {
        int ao = arow[i] * 64 + ((kgr ^ (arow[i] & 7)) * 8);
        ah8[i] = *reinterpret_cast<const short8*>(As_h + ao);
        al8[i] = *reinterpret_cast<const short8*>(As_l + ao);
        int bo = brow[i] * 64 + ((kgr ^ (brow[i] & 7)) * 8);
        bh8[i] = *reinterpret_cast<const short8*>(Bs_h + bo);
        bl8[i] = *reinterpret_cast<const short8*>(Bs_l + bo);
      }
      __builtin_amdgcn_s_setprio(1);
#pragma unroll
      for (int i = 0; i < 2; ++i)
#pragma unroll
        for (int j = 0; j < 2; ++j) {
          acc[i][j] = __builtin_amdgcn_mfma_f32_16x16x32_bf16(
              ah8[i], bh8[j], acc[i][j], 0, 0, 0);
          acc[i][j] = __builtin_amdgcn_mfma_f32_16x16x32_bf16(
              ah8[i], bl8[j], acc[i][j], 0, 0, 0);
          acc[i][j] = __builtin_amdgcn_mfma_f32_16x16x32_bf16(
              al8[i], bh8[j], acc[i][j], 0, 0, 0);
        }
      __builtin_amdgcn_s_setprio(0);
    }
  }

  // ---- epilogue ----
#pragma unroll
  for (int i = 0; i < 2; ++i)
#pragma unroll
    for (int j = 0; j < 2; ++j) {
      int gr = row0 + wr * 32 + i * 16 + ksel * 4;
      int gc = col0 + wc * 32 + j * 16 + rsel;
      float bb = bias[gc];
      bool dt = (ACT == 1) || (ACT == 2 && !(gc >= 512 && gc < 1024));
#pragma unroll
      for (int rg = 0; rg < 4; ++rg) {
        float v = acc[i][j][rg] + bb;
        if (dt) v = tanhf(v);
        if constexpr (OUTF32) {
          outf[(size_t)(gr + rg) * ldo + gc] = v;
        } else {
          unsigned short h, l;
          split2(v, h, l);
          oh[(size_t)(gr + rg) * ldo + gc] = h;
          ol[(size_t)(gr + rg) * ldo + gc] = l;
        }
      }
    }
}

// ---------------------------------------------------------------------------
// grad of action (+ split mirrors), 128 threads per row
// ---------------------------------------------------------------------------
__device__ __forceinline__ void grad_from_lds(
    const float* xsh, float* sp, float beta, int row,
    float* __restrict__ g, unsigned short* __restrict__ gh,
    unsigned short* __restrict__ gl)
{
  int s0 = threadIdx.x * 2;
#pragma unroll
  for (int u = 0; u < 2; ++u) {
    int s = s0 + u, tt = s >> 4, l = s & 15;
    float p = xsh[s * 2] - xsh[s * 2 + 1]
            - xsh[(tt * 16 + ((l + 1) & 15)) * 2]
            + xsh[(((tt + 1) & 15) * 16 + l) * 2 + 1];
    sp[s] = sinf(p);
  }
  __syncthreads();
  float* gr = g + (size_t)row * ND;
  unsigned short* ghr = gh + (size_t)row * ND;
  unsigned short* glr = gl + (size_t)row * ND;
#pragma unroll
  for (int u = 0; u < 2; ++u) {
    int s = s0 + u, tt = s >> 4, l = s & 15;
    float g0 = beta * (sp[s] - sp[tt * 16 + ((l - 1) & 15)]);
    float g1 = beta * (sp[((tt - 1) & 15) * 16 + l] - sp[s]);
    gr[s * 2] = g0;
    gr[s * 2 + 1] = g1;
    unsigned short h0, l0, h1v, l1v;
    split2(g0, h0, l0);
    split2(g1, h1v, l1v);
    ghr[s * 2] = h0; glr[s * 2] = l0;
    ghr[s * 2 + 1] = h1v; glr[s * 2 + 1] = l1v;
  }
}

__global__ __launch_bounds__(128) void grad_k(
    const float* __restrict__ xs, const float* __restrict__ betap,
    float* __restrict__ g, unsigned short* __restrict__ gh,
    unsigned short* __restrict__ gl)
{
  __shared__ float xsh[512];
  __shared__ float sp[256];
  int row = blockIdx.x, c = threadIdx.x << 2;
  float4 x4 = *reinterpret_cast<const float4*>(xs + (size_t)row * ND + c);
  xsh[c] = x4.x; xsh[c + 1] = x4.y; xsh[c + 2] = x4.z; xsh[c + 3] = x4.w;
  __syncthreads();
  grad_from_lds(xsh, sp, betap[0], row, g, gh, gl);
}

// ---------------------------------------------------------------------------
// init: copy states, split mirrors, pre-masked x for the first xnet
// ---------------------------------------------------------------------------
__global__ __launch_bounds__(128) void init_k(
    const float* __restrict__ x_in, const float* __restrict__ v_in,
    const float* __restrict__ m0F, const float* __restrict__ m0B,
    float* __restrict__ xs, float* __restrict__ vs,
    unsigned short* __restrict__ xh, unsigned short* __restrict__ xl,
    unsigned short* __restrict__ xmh, unsigned short* __restrict__ xml,
    unsigned short* __restrict__ vh, unsigned short* __restrict__ vl,
    float* __restrict__ ld)
{
  int row = blockIdx.x;
  bool fwd = row < NB;
  int c = threadIdx.x << 2;
  size_t off = (size_t)row * ND + c;
  const float* xr = x_in + (size_t)(fwd ? row : row - NB) * ND + c;
  const float* vr = v_in + off;
  const float* mk = (fwd ? m0F : m0B) + c;
  float4 x4 = *reinterpret_cast<const float4*>(xr);
  float4 v4 = *reinterpret_cast<const float4*>(vr);
  float4 m4 = *reinterpret_cast<const float4*>(mk);
  float xx[4] = {x4.x, x4.y, x4.z, x4.w};
  float vv[4] = {v4.x, v4.y, v4.z, v4.w};
  float mm[4] = {m4.x, m4.y, m4.z, m4.w};
  ushort4 xhv, xlv, xmhv, xmlv, vhv, vlv;
  unsigned short* ph = (unsigned short*)&xhv;
  unsigned short* pl = (unsigned short*)&xlv;
  unsigned short* pmh = (unsigned short*)&xmhv;
  unsigned short* pml = (unsigned short*)&xmlv;
  unsigned short* pvh = (unsigned short*)&vhv;
  unsigned short* pvl = (unsigned short*)&vlv;
#pragma unroll
  for (int j = 0; j < 4; ++j) {
    float m = fwd ? mm[j] : 1.f - mm[j];   // bwd first mask inverted
    split2(xx[j], ph[j], pl[j]);
    split2(m * xx[j], pmh[j], pml[j]);
    split2(vv[j], pvh[j], pvl[j]);
  }
  *reinterpret_cast<float4*>(xs + off) = make_float4(xx[0], xx[1], xx[2], xx[3]);
  *reinterpret_cast<float4*>(vs + off) = make_float4(vv[0], vv[1], vv[2], vv[3]);
  *reinterpret_cast<ushort4*>(xh + off) = xhv;
  *reinterpret_cast<ushort4*>(xl + off) = xlv;
  *reinterpret_cast<ushort4*>(xmh + off) = xmhv;
  *reinterpret_cast<ushort4*>(xml + off) = xmlv;
  *reinterpret_cast<ushort4*>(vh + off) = vhv;
  *reinterpret_cast<ushort4*>(vl + off) = vlv;
  if (threadIdx.x == 0) ld[row] = 0.f;
}

// ---------------------------------------------------------------------------
// v update (optionally applied twice: trailing half-step of step s + leading
// half-step of step s+1 use identical S,T,Q,g); split mirrors.
// ---------------------------------------------------------------------------
__global__ __launch_bounds__(128) void upd_v_k(
    float* __restrict__ vs, const float* __restrict__ g,
    const float* __restrict__ STQ,
    const float* __restrict__ epsp, float* __restrict__ ld,
    unsigned short* __restrict__ vh, unsigned short* __restrict__ vl,
    int twice)
{
  int row = blockIdx.x;
  bool fwd = row < NB;
  int c = threadIdx.x << 2;
  float eps = epsp[0];
  size_t off = (size_t)row * ND + c;
  const float* sr = STQ + (size_t)row * 1536;
  float4 v4 = *reinterpret_cast<float4*>(vs + off);
  float4 g4 = *reinterpret_cast<const float4*>(g + off);
  float4 S4 = *reinterpret_cast<const float4*>(sr + c);
  float4 T4 = *reinterpret_cast<const float4*>(sr + 512 + c);
  float4 Q4 = *reinterpret_cast<const float4*>(sr + 1024 + c);
  float vv[4] = {v4.x, v4.y, v4.z, v4.w};
  float gg[4] = {g4.x, g4.y, g4.z, g4.w};
  float ss[4] = {S4.x, S4.y, S4.z, S4.w};
  float tt[4] = {T4.x, T4.y, T4.z, T4.w};
  float qq[4] = {Q4.x, Q4.y, Q4.z, Q4.w};
  float scsum = 0.f;
  ushort4 hv, lv;
  unsigned short* ph = (unsigned short*)&hv;
  unsigned short* pl = (unsigned short*)&lv;
#pragma unroll
  for (int j = 0; j < 4; ++j) {
    float sc = (fwd ? 0.5f : -0.5f) * eps * ss[j];
    float F = gg[j] * expf(eps * qq[j]) + tt[j];
    vv[j] = fwd ? vv[j] * expf(sc) - 0.5f * eps * F
                : expf(sc) * (vv[j] + 0.5f * eps * F);
    scsum += sc;
    if (twice) {
      vv[j] = fwd ? vv[j] * expf(sc) - 0.5f * eps * F
                  : expf(sc) * (vv[j] + 0.5f * eps * F);
      scsum += sc;
    }
    split2(vv[j], ph[j], pl[j]);
  }
  *reinterpret_cast<float4*>(vs + off) = make_float4(vv[0], vv[1], vv[2], vv[3]);
  *reinterpret_cast<ushort4*>(vh + off) = hv;
  *reinterpret_cast<ushort4*>(vl + off) = lv;
  for (int o = 32; o > 0; o >>= 1) scsum += __shfl_down(scsum, o);
  __shared__ float part[2];
  if ((threadIdx.x & 63) == 0) part[threadIdx.x >> 6] = scsum;
  __syncthreads();
  if (threadIdx.x == 0) ld[row] += part[0] + part[1];
}

// ---------------------------------------------------------------------------
// x update + fused grad recompute + split mirrors (x, masked-x-for-next, g)
// ---------------------------------------------------------------------------
__global__ __launch_bounds__(128) void upd_x_k(
    float* __restrict__ xs, const float* __restrict__ vs,
    const float* __restrict__ STQ,
    const float* __restrict__ maskF, int invF,
    const float* __restrict__ maskB, int invB,
    const float* __restrict__ nmF, int niF,
    const float* __restrict__ nmB, int niB,
    const float* __restrict__ epsp, const float* __restrict__ betap,
    float* __restrict__ g, float* __restrict__ ld,
    unsigned short* __restrict__ xh, unsigned short* __restrict__ xl,
    unsigned short* __restrict__ xmh, unsigned short* __restrict__ xml,
    unsigned short* __restrict__ gh, unsigned short* __restrict__ gl)
{
  __shared__ float xsh[512];
  __shared__ float sp[256];
  int row = blockIdx.x;
  bool fwd = row < NB;
  const float* mk = fwd ? maskF : maskB;
  const float* nmk = fwd ? nmF : nmB;
  int inv = fwd ? invF : invB;
  int ninv = fwd ? niF : niB;
  int c = threadIdx.x << 2;
  float eps = epsp[0];
  size_t off = (size_t)row * ND + c;
  const float* sr = STQ + (size_t)row * 1536;
  float4 x4 = *reinterpret_cast<float4*>(xs + off);
  float4 v4 = *reinterpret_cast<const float4*>(vs + off);
  float4 m4 = *reinterpret_cast<const float4*>(mk + c);
  float4 n4 = *reinterpret_cast<const float4*>(nmk + c);
  float4 S4 = *reinterpret_cast<const float4*>(sr + c);
  float4 T4 = *reinterpret_cast<const float4*>(sr + 512 + c);
  float4 Q4 = *reinterpret_cast<const float4*>(sr + 1024 + c);
  float xx[4] = {x4.x, x4.y, x4.z, x4.w};
  float vv[4] = {v4.x, v4.y, v4.z, v4.w};
  float mm[4] = {m4.x, m4.y, m4.z, m4.w};
  float nn[4] = {n4.x, n4.y, n4.z, n4.w};
  float ss[4] = {S4.x, S4.y, S4.z, S4.w};
  float tt[4] = {T4.x, T4.y, T4.z, T4.w};
  float qq[4] = {Q4.x, Q4.y, Q4.z, Q4.w};
  float scsum = 0.f;
  float xn[4];
  ushort4 hv, lv, mhv, mlv;
  unsigned short* ph = (unsigned short*)&hv;
  unsigned short* pl = (unsigned short*)&lv;
  unsigned short* pmh = (unsigned short*)&mhv;
  unsigned short* pml = (unsigned short*)&mlv;
#pragma unroll
  for (int j = 0; j < 4; ++j) {
    float m = inv ? 1.f - mm[j] : mm[j];
    float mb = 1.f - m;
    float es = eps * ss[j];
    float F = vv[j] * expf(eps * qq[j]) + tt[j];
    float t;
    if (fwd) {
      t = m * xx[j] + mb * (xx[j] * expf(es) + eps * F);
      scsum += mb * es;
    } else {
      t = m * xx[j] + mb * (expf(-es) * (xx[j] - eps * F));
      scsum -= mb * es;
    }
    xn[j] = wrap_angle(t);
    xsh[c + j] = xn[j];
    float nm = ninv ? 1.f - nn[j] : nn[j];
    split2(xn[j], ph[j], pl[j]);
    split2(nm * xn[j], pmh[j], pml[j]);
  }
  *reinterpret_cast<float4*>(xs + off) = make_float4(xn[0], xn[1], xn[2], xn[3]);
  *reinterpret_cast<ushort4*>(xh + off) = hv;
  *reinterpret_cast<ushort4*>(xl + off) = lv;
  *reinterpret_cast<ushort4*>(xmh + off) = mhv;
  *reinterpret_cast<ushort4*>(xml + off) = mlv;
  __syncthreads();
  grad_from_lds(xsh, sp, betap[0], row, g, gh, gl);
  for (int o = 32; o > 0; o >>= 1) scsum += __shfl_down(scsum, o);
  __shared__ float part[2];
  if ((threadIdx.x & 63) == 0) part[threadIdx.x >> 6] = scsum;
  __syncthreads();
  if (threadIdx.x == 0) ld[row] += part[0] + part[1];
}

// ---------------------------------------------------------------------------
// finalize (stacked state)
// ---------------------------------------------------------------------------
__global__ __launch_bounds__(256) void finalize_k(
    const float* __restrict__ x_in, const float* __restrict__ v_in,
    const float* __restrict__ xs, const float* __restrict__ vs,
    const float* __restrict__ ld,
    const float* __restrict__ rdir, const float* __restrict__ racc,
    const float* __restrict__ betap,
    float* __restrict__ out_x, float* __restrict__ out_px,
    float* __restrict__ out_sld)
{
  int b = blockIdx.x, t = threadIdx.x;
  bool fwd = rdir[b] < 0.5f;
  int prow = fwd ? b : NB + b;
  const float* xp = xs + (size_t)prow * ND;
  const float* vp = vs + (size_t)prow * ND;
  const float* vi = v_in + (size_t)(fwd ? 0 : NB) * ND + (size_t)b * ND;
  float sld = ld[prow];
  __shared__ float xs0[512], xs1[512];
  const float* xr = x_in + (size_t)b * ND;
  xs0[t] = xr[t]; xs0[t + 256] = xr[t + 256];
  xs1[t] = xp[t]; xs1[t + 256] = xp[t + 256];
  __syncthreads();
  int tt = t >> 4, l = t & 15;
  int i00 = t * 2, i01 = t * 2 + 1;
  int i10 = (tt * 16 + ((l + 1) & 15)) * 2;
  int i11 = (((tt + 1) & 15) * 16 + l) * 2 + 1;
  float p0 = xs0[i00] - xs0[i01] - xs0[i10] + xs0[i11];
  float p1 = xs1[i00] - xs1[i01] - xs1[i10] + xs1[i11];
  float r0 = 1.f - cosf(p0);
  float r1 = 1.f - cosf(p1);
  float a0v = vi[t], a1v = vi[t + 256];
  float b0v = vp[t], b1v = vp[t + 256];
  float svi = a0v * a0v + a1v * a1v;
  float svp = b0v * b0v + b1v * b1v;
  for (int o = 32; o > 0; o >>= 1) {
    r0  += __shfl_down(r0, o);
    r1  += __shfl_down(r1, o);
    svi += __shfl_down(svi, o);
    svp += __shfl_down(svp, o);
  }
  __shared__ float red[4][4];
  if ((t & 63) == 0) {
    int w = t >> 6;
    red[w][0] = r0; red[w][1] = r1; red[w][2] = svi; red[w][3] = svp;
  }
  __syncthreads();
  __shared__ float px_s;
  if (t == 0) {
    float R0 = 0, R1 = 0, SI = 0, SP = 0;
    for (int w = 0; w < 4; ++w) {
      R0 += red[w][0]; R1 += red[w][1]; SI += red[w][2]; SP += red[w][3];
    }
    float beta = betap[0];
    float h_init = beta * R0 + 0.5f * SI;
    float h_prop = beta * R1 + 0.5f * SP;
    px_s = expf(fminf(h_init - h_prop + sld, 0.f));
  }
  __syncthreads();
  float px = px_s;
  bool ma = racc[b] < px;
  float* ox = out_x + (size_t)b * ND;
  ox[t]       = wrap_angle(ma ? xs1[t]       : xs0[t]);
  ox[t + 256] = wrap_angle(ma ? xs1[t + 256] : xs0[t + 256]);
  if (t == 0) {
    out_px[b] = px;
    out_sld[b] = ma ? sld : 0.f;
  }
}

}  // namespace

extern "C" void kernel_launch(void* const* d_in, const int* in_sizes, int n_in,
                              void* d_out, int out_size, void* d_ws, size_t ws_size,
                              hipStream_t stream)
{
  const float* x_in = (const float*)d_in[0];
  const float* v_in = (const float*)d_in[1];
  const float* epsp = (const float*)d_in[2];
  const float* betap = (const float*)d_in[3];
  const float* rdir = (const float*)d_in[4];
  const float* racc = (const float*)d_in[5];
  const float* masks = (const float*)d_in[6];
  const float* xW1 = (const float*)d_in[7];
  const float* xb1 = (const float*)d_in[8];
  const float* xW2 = (const float*)d_in[9];
  const float* xb2 = (const float*)d_in[10];
  const float* xWs = (const float*)d_in[11];
  const float* xbs = (const float*)d_in[12];
  const float* xWt = (const float*)d_in[13];
  const float* xbt = (const float*)d_in[14];
  const float* xWq = (const float*)d_in[15];
  const float* xbq = (const float*)d_in[16];
  const float* vW1 = (const float*)d_in[17];
  const float* vb1 = (const float*)d_in[18];
  const float* vW2 = (const float*)d_in[19];
  const float* vb2 = (const float*)d_in[20];
  const float* vWs = (const float*)d_in[21];
  const float* vbs = (const float*)d_in[22];
  const float* vWt = (const float*)d_in[23];
  const float* vbt = (const float*)d_in[24];
  const float* vWq = (const float*)d_in[25];
  const float* vbq = (const float*)d_in[26];

  char* base = (char*)d_ws;
  auto alloc = [&](size_t bytes) {
    char* r = base;
    base += (bytes + 255) & ~(size_t)255;
    return r;
  };
  float* xs = (float*)alloc((size_t)NM * ND * 4);
  float* vs = (float*)alloc((size_t)NM * ND * 4);
  float* g  = (float*)alloc((size_t)NM * ND * 4);
  float* ld = (float*)alloc((size_t)NM * 4);
  unsigned short* xh  = (unsigned short*)alloc((size_t)NM * ND * 2);
  unsigned short* xl  = (unsigned short*)alloc((size_t)NM * ND * 2);
  unsigned short* xmh = (unsigned short*)alloc((size_t)NM * ND * 2);
  unsigned short* xml = (unsigned short*)alloc((size_t)NM * ND * 2);
  unsigned short* vh  = (unsigned short*)alloc((size_t)NM * ND * 2);
  unsigned short* vl  = (unsigned short*)alloc((size_t)NM * ND * 2);
  unsigned short* gh  = (unsigned short*)alloc((size_t)NM * ND * 2);
  unsigned short* gl  = (unsigned short*)alloc((size_t)NM * ND * 2);
  unsigned short* h1h = (unsigned short*)alloc((size_t)NM * NH * 2);
  unsigned short* h1l = (unsigned short*)alloc((size_t)NM * NH * 2);
  unsigned short* h2h = (unsigned short*)alloc((size_t)NM * NH * 2);
  unsigned short* h2l = (unsigned short*)alloc((size_t)NM * NH * 2);
  float* STQ = (float*)alloc((size_t)NM * 1536 * 4);
  unsigned short* xW1h = (unsigned short*)alloc((size_t)NH * KTOT * 2);
  unsigned short* xW1l = (unsigned short*)alloc((size_t)NH * KTOT * 2);
  unsigned short* xW2h = (unsigned short*)alloc((size_t)NH * KTOT * 2);
  unsigned short* xW2l = (unsigned short*)alloc((size_t)NH * KTOT * 2);
  unsigned short* xWsh = (unsigned short*)alloc((size_t)1536 * KTOT * 2);
  unsigned short* xWsl = (unsigned short*)alloc((size_t)1536 * KTOT * 2);
  unsigned short* vW1h = (unsigned short*)alloc((size_t)NH * KTOT * 2);
  unsigned short* vW1l = (unsigned short*)alloc((size_t)NH * KTOT * 2);
  unsigned short* vW2h = (unsigned short*)alloc((size_t)NH * KTOT * 2);
  unsigned short* vW2l = (unsigned short*)alloc((size_t)NH * KTOT * 2);
  unsigned short* vWsh = (unsigned short*)alloc((size_t)1536 * KTOT * 2);
  unsigned short* vWsl = (unsigned short*)alloc((size_t)1536 * KTOT * 2);
  float* bstq_x = (float*)alloc(1536 * 4);
  float* bstq_v = (float*)alloc(1536 * 4);

  // ---- weight prep ----
  dim3 tb(32, 8);
  tcvt_k<<<dim3(32, 32), tb, 0, stream>>>(xW1, 1024, xW1h, xW1l, 0);
  tcvt_k<<<dim3(32, 32), tb, 0, stream>>>(xW2, 1024, xW2h, xW2l, 0);
  tcvt_k<<<dim3(16, 32), tb, 0, stream>>>(xWs, 512, xWsh, xWsl, 0);
  tcvt_k<<<dim3(16, 32), tb, 0, stream>>>(xWt, 512, xWsh, xWsl, 512);
  tcvt_k<<<dim3(16, 32), tb, 0, stream>>>(xWq, 512, xWsh, xWsl, 1024);
  tcvt_k<<<dim3(32, 32), tb, 0, stream>>>(vW1, 1024, vW1h, vW1l, 0);
  tcvt_k<<<dim3(32, 32), tb, 0, stream>>>(vW2, 1024, vW2h, vW2l, 0);
  tcvt_k<<<dim3(16, 32), tb, 0, stream>>>(vWs, 512, vWsh, vWsl, 0);
  tcvt_k<<<dim3(16, 32), tb, 0, stream>>>(vWt, 512, vWsh, vWsl, 512);
  tcvt_k<<<dim3(16, 32), tb, 0, stream>>>(vWq, 512, vWsh, vWsl, 1024);
  hipMemcpyAsync(bstq_x,        xbs, 512 * 4, hipMemcpyDeviceToDevice, stream);
  hipMemcpyAsync(bstq_x + 512,  xbt, 512 * 4, hipMemcpyDeviceToDevice, stream);
  hipMemcpyAsync(bstq_x + 1024, xbq, 512 * 4, hipMemcpyDeviceToDevice, stream);
  hipMemcpyAsync(bstq_v,        vbs, 512 * 4, hipMemcpyDeviceToDevice, stream);
  hipMemcpyAsync(bstq_v + 512,  vbt, 512 * 4, hipMemcpyDeviceToDevice, stream);
  hipMemcpyAsync(bstq_v + 1024, vbq, 512 * 4, hipMemcpyDeviceToDevice, stream);

  // ---- state init (rows 0..1023 fwd, 1024..2047 bwd) ----
  init_k<<<NM, 128, 0, stream>>>(x_in, v_in, masks, masks + 9 * ND,
                                 xs, vs, xh, xl, xmh, xml, vh, vl, ld);
  grad_k<<<NM, 128, 0, stream>>>(xs, betap, g, gh, gl);

  auto vnet = [&]() {
    gemm_k<1, 0><<<dim3(16, 32), 256, 0, stream>>>(
        xh, xl, gh, gl, 512, vW1h, vW1l, vb1, nullptr, h1h, h1l, NH);
    gemm_k<1, 0><<<dim3(16, 32), 256, 0, stream>>>(
        h1h, h1l, h1h + 512, h1l + 512, 1024, vW2h, vW2l, vb2,
        nullptr, h2h, h2l, NH);
    gemm_k<2, 1><<<dim3(24, 32), 256, 0, stream>>>(
        h2h, h2l, h2h + 512, h2l + 512, 1024, vWsh, vWsl, bstq_v,
        STQ, nullptr, nullptr, 1536);
  };
  auto xnet = [&]() {
    gemm_k<1, 0><<<dim3(16, 32), 256, 0, stream>>>(
        vh, vl, xmh, xml, 512, xW1h, xW1l, xb1, nullptr, h1h, h1l, NH);
    gemm_k<1, 0><<<dim3(16, 32), 256, 0, stream>>>(
        h1h, h1l, h1h + 512, h1l + 512, 1024, xW2h, xW2l, xb2,
        nullptr, h2h, h2l, NH);
    gemm_k<2, 1><<<dim3(24, 32), 256, 0, stream>>>(
        h2h, h2l, h2h + 512, h2l + 512, 1024, xWsh, xWsl, bstq_x,
        STQ, nullptr, nullptr, 1536);
  };

  // STQ_v for x_0, then step 0's leading v half-step (single)
  vnet();
  upd_v_k<<<NM, 128, 0, stream>>>(vs, g, STQ, epsp, ld, vh, vl, 0);
  for (int s = 0; s < 10; ++s) {
    const float* mF = masks + (size_t)s * ND;
    const float* mB = masks + (size_t)(9 - s) * ND;
    const float* mFn = masks + (size_t)((s + 1 < 10) ? s + 1 : 0) * ND;
    const float* mBn = masks + (size_t)((s + 1 < 10) ? 8 - s : 0) * ND;
    // x sub-step 1: fwd m, bwd 1-m; next consumer mask: fwd 1-m, bwd m
    xnet();
    upd_x_k<<<NM, 128, 0, stream>>>(xs, vs, STQ, mF, 0, mB, 1, mF, 1, mB, 0,
                                    epsp, betap, g, ld,
                                    xh, xl, xmh, xml, gh, gl);
    // x sub-step 2: fwd 1-m, bwd m; next: step s+1 sub1 (fwd m', bwd 1-m')
    xnet();
    upd_x_k<<<NM, 128, 0, stream>>>(xs, vs, STQ, mF, 1, mB, 0, mFn, 0, mBn, 1,
                                    epsp, betap, g, ld,
                                    xh, xl, xmh, xml, gh, gl);
    // vnet on NEW x serves trailing half-step of s AND leading of s+1
    vnet();
    upd_v_k<<<NM, 128, 0, stream>>>(vs, g, STQ, epsp, ld, vh, vl,
                                    (s < 9) ? 1 : 0);
  }

  float* out_x = (float*)d_out;
  float* out_px = out_x + (size_t)NB * ND;
  float* out_sld = out_px + NB;
  finalize_k<<<NB, 256, 0, stream>>>(x_in, v_in, xs, vs, ld, rdir, racc, betap,
                                     out_x, out_px, out_sld);
}